// Round 10
// baseline (582.951 us; speedup 1.0000x reference)
//
#include <hip/hip_runtime.h>

#define N_NODES 131072
#define E_EDGES 524288
#define B_GR    2048
#define H_DIM   128
#define NF_DIM  30
#define GF_DIM  4415
#define GF_PAD  4416            // 138*32 = 69*64
#define BN_SCALE 0.9999950000374997f   // 1/sqrt(1+1e-5)
#define NSPLIT  32              // gene GEMM k-splits (4 blocks/CU)

typedef __bf16 bf16x8 __attribute__((ext_vector_type(8)));
typedef float  f32x4  __attribute__((ext_vector_type(4)));
typedef unsigned int uint32;
typedef uint32 u32x4 __attribute__((ext_vector_type(4)));

__device__ __forceinline__ void split2(float x, __bf16& hi, __bf16& lo){
    hi = (__bf16)x;
    lo = (__bf16)(x - (float)hi);
}
__device__ __forceinline__ uint32 bfbits(float x){
    __bf16 h = (__bf16)x;
    return (uint32)__builtin_bit_cast(unsigned short, h);
}
// packed uint32: low 16 bits = even col, high 16 bits = odd col
__device__ __forceinline__ float unpack_even(uint32 u){ return __uint_as_float(u<<16); }
__device__ __forceinline__ float unpack_odd (uint32 u){ return __uint_as_float(u & 0xffff0000u); }
__device__ __forceinline__ uint32 pack2(float e, float o){ return bfbits(e) | (bfbits(o)<<16); }

// ---------------- graph prep ----------------

__global__ void k_zero2(int* __restrict__ a, int na, float* __restrict__ b, int nb){
    int i = blockIdx.x*256 + threadIdx.x;
    if(i < na) a[i] = 0;
    int j = i - na;
    if(j >= 0 && j < nb) b[j] = 0.f;
}

__global__ void k_count(const int* __restrict__ dst, int* __restrict__ counts){
    int e = blockIdx.x*256 + threadIdx.x;
    if(e < E_EDGES) atomicAdd(&counts[dst[e]], 1);
}

__global__ void k_scan1(int* __restrict__ counts, int* __restrict__ bsums){
    __shared__ int s[1024];
    int t = threadIdx.x;
    int gi = blockIdx.x*1024 + t;
    int v = counts[gi];
    s[t] = v; __syncthreads();
    for(int off=1; off<1024; off<<=1){
        int x = (t>=off) ? s[t-off] : 0;
        __syncthreads();
        s[t] += x;
        __syncthreads();
    }
    counts[gi] = s[t] - v;
    if(t == 1023) bsums[blockIdx.x] = s[t];
}

__global__ void k_scan2(int* __restrict__ bsums){
    __shared__ int s[128];
    int t = threadIdx.x;
    int v = bsums[t]; s[t] = v; __syncthreads();
    for(int off=1; off<128; off<<=1){
        int x = (t>=off) ? s[t-off] : 0;
        __syncthreads();
        s[t] += x;
        __syncthreads();
    }
    bsums[t] = s[t] - v;
}

// merged: rowptr + dinv + cursor (counts is read-only here; cursor is a separate buffer)
__global__ void k_scan3(const int* __restrict__ counts, const int* __restrict__ bsums,
                        int* __restrict__ rowptr, float* __restrict__ dinv,
                        int* __restrict__ cursor){
    int i = blockIdx.x*1024 + threadIdx.x;
    int r0 = counts[i] + bsums[blockIdx.x];
    int r1;
    if(i == N_NODES-1){
        r1 = E_EDGES;
        rowptr[N_NODES] = E_EDGES;
    } else {
        int ip = i + 1;
        int nb = (threadIdx.x == 1023) ? blockIdx.x + 1 : blockIdx.x;
        r1 = counts[ip] + bsums[nb];
    }
    rowptr[i] = r0;
    dinv[i] = rsqrtf((float)(r1 - r0) + 1.0f);
    cursor[i] = r0;
}

__global__ void k_fill(const int* __restrict__ src, const int* __restrict__ dst,
                       int* __restrict__ cursor, int* __restrict__ csr){
    int e = blockIdx.x*256 + threadIdx.x;
    if(e < E_EDGES){
        int p = atomicAdd(&cursor[dst[e]], 1);
        csr[p] = src[e];
    }
}

// ---------------- combined weight split: Wge1 (LDS tile transpose) + Wg + Wemb ----------------

__global__ void k_split_weights(const float* __restrict__ Wge1, __bf16* __restrict__ wth,
                                __bf16* __restrict__ wtl,
                                const float* __restrict__ Wg, __bf16* __restrict__ gth,
                                __bf16* __restrict__ gtl,
                                const float* __restrict__ Wemb, __bf16* __restrict__ eth,
                                __bf16* __restrict__ etl){
    __shared__ float sTile[64][65];
    unsigned bid = blockIdx.x;
    int tid = threadIdx.x;
    if(bid < 276u){
        // Wge1: 64(k) x 64(c) tile transpose; coalesced reads AND writes
        int kt = bid % 69u, ct = bid / 69u;
        int k0 = kt*64, c0 = ct*64;
        #pragma unroll
        for(int i=0;i<16;i++){
            int idx = i*256 + tid;
            int kk = idx >> 6, cc = idx & 63;
            int k = k0 + kk;
            sTile[kk][cc] = (k < GF_DIM) ? Wge1[(size_t)k*256 + c0 + cc] : 0.f;
        }
        __syncthreads();
        #pragma unroll
        for(int i=0;i<16;i++){
            int idx = i*256 + tid;
            int cc = idx >> 6, kk = idx & 63;
            float v = sTile[kk][cc];
            size_t o = (size_t)(c0 + cc)*GF_PAD + k0 + kk;
            split2(v, wth[o], wtl[o]);
        }
    } else if(bid < 276u + 192u){
        int idx = (bid - 276u)*256 + tid;            // 3*128*128
        int l = idx >> 14, i = idx & 16383;
        int k = i >> 7, c = i & 127;
        float v = Wg[idx];
        int o = (l << 14) + (c << 7) + k;            // transposed: [l][c][k]
        split2(v, gth[o], gtl[o]);
    } else {
        int idx = (bid - 468u)*256 + tid;            // 128*32  (c-major, k padded)
        int c = idx >> 5, k = idx & 31;
        float v = (k < NF_DIM) ? Wemb[k*H_DIM + c] : 0.f;
        split2(v, eth[idx], etl[idx]);
    }
}

// ---------------- embedding via MFMA (fused x split):  relu(x @ W_emb + b) ----------------

__global__ __launch_bounds__(256)
void k_emb_mfma(const float* __restrict__ x,
                const __bf16* __restrict__ wth, const __bf16* __restrict__ wtl,
                const float* __restrict__ bias, uint32* __restrict__ Hh2,
                uint32* __restrict__ Hl2){
    __shared__ float sT[4][32*68];
    int wave = threadIdx.x >> 6, lane = threadIdx.x & 63;
    int lr = lane & 15, lq = lane >> 4;
    int rbase = blockIdx.x*128 + wave*32;
    const f32x4 zero4 = {0.f,0.f,0.f,0.f};
    const float* xr0 = x + (size_t)(rbase + lr)*NF_DIM;
    const float* xr1 = x + (size_t)(rbase + 16 + lr)*NF_DIM;
    bf16x8 A0h, A0l, A1h, A1l;
    #pragma unroll
    for(int t=0;t<8;t++){
        int k = lq*8 + t;
        float v0 = (k < NF_DIM) ? xr0[k] : 0.f;
        float v1 = (k < NF_DIM) ? xr1[k] : 0.f;
        __bf16 h, l;
        split2(v0, h, l); A0h[t] = h; A0l[t] = l;
        split2(v1, h, l); A1h[t] = h; A1l[t] = l;
    }
    int orow = lane >> 3;          // 0..7
    int oq   = lane & 7;           // 0..7
    float* sW = sT[wave];
    for(int ph=0; ph<2; ph++){
        #pragma unroll
        for(int cc=0; cc<4; cc++){
            int col = (ph*4+cc)*16 + lr;
            bf16x8 Bh = *(const bf16x8*)(wth + col*32 + lq*8);
            bf16x8 Bl = *(const bf16x8*)(wtl + col*32 + lq*8);
            f32x4 a0 = zero4, a1 = zero4;
            a0 = __builtin_amdgcn_mfma_f32_16x16x32_bf16(A0h, Bh, a0, 0,0,0);
            a0 = __builtin_amdgcn_mfma_f32_16x16x32_bf16(A0l, Bh, a0, 0,0,0);
            a0 = __builtin_amdgcn_mfma_f32_16x16x32_bf16(A0h, Bl, a0, 0,0,0);
            a1 = __builtin_amdgcn_mfma_f32_16x16x32_bf16(A1h, Bh, a1, 0,0,0);
            a1 = __builtin_amdgcn_mfma_f32_16x16x32_bf16(A1l, Bh, a1, 0,0,0);
            a1 = __builtin_amdgcn_mfma_f32_16x16x32_bf16(A1h, Bl, a1, 0,0,0);
            #pragma unroll
            for(int r=0;r<4;r++){
                sW[(lq*4+r)*68 + cc*16 + lr]    = a0[r];
                sW[(16+lq*4+r)*68 + cc*16 + lr] = a1[r];
            }
        }
        __syncthreads();
        int cg = ph*64 + oq*8;
        float bb[8];
        *(float4*)&bb[0] = *(const float4*)(bias + cg);
        *(float4*)&bb[4] = *(const float4*)(bias + cg + 4);
        #pragma unroll
        for(int i=0;i<4;i++){
            int row = i*8 + orow;
            float v[8];
            *(float4*)&v[0] = *(float4*)&sW[row*68 + oq*8];
            *(float4*)&v[4] = *(float4*)&sW[row*68 + oq*8 + 4];
            uint32 oh[4], ol[4];
            #pragma unroll
            for(int p=0;p<4;p++){
                float ve = fmaxf(v[2*p]   + bb[2*p],   0.f);
                float vo = fmaxf(v[2*p+1] + bb[2*p+1], 0.f);
                uint32 he = bfbits(ve), ho = bfbits(vo);
                oh[p] = he | (ho<<16);
                float le = ve - __uint_as_float(he<<16);
                float lo = vo - __uint_as_float(ho<<16);
                ol[p] = pack2(le, lo);
            }
            size_t oidx = (size_t)(rbase + row)*64 + (cg>>1);
            *(uint4*)(Hh2 + oidx) = make_uint4(oh[0],oh[1],oh[2],oh[3]);
            *(uint4*)(Hl2 + oidx) = make_uint4(ol[0],ol[1],ol[2],ol[3]);
        }
        __syncthreads();
    }
}

// ---------------- FUSED GCN layer (frozen at verified 82.9 µs version) ----------------

struct MetaA {
    int   j0A, cA, j0B, cB;
    float dnA, dnB;
    uint32 shA, slA, shB, slB;
};

__device__ __forceinline__ void load_metaA(MetaA& m, int nA, int lane,
                                           const int* __restrict__ rowptr,
                                           const float* __restrict__ dinv,
                                           const uint32* __restrict__ Hh2,
                                           const uint32* __restrict__ Hl2){
    int nB = nA + 8;
    int a0 = rowptr[nA], a1 = rowptr[nA+1];
    int b0 = rowptr[nB], b1 = rowptr[nB+1];
    m.j0A = a0; m.cA = a1 - a0;
    m.j0B = b0; m.cB = b1 - b0;
    m.dnA = dinv[nA]; m.dnB = dinv[nB];
    size_t iA = (size_t)nA*64 + lane, iB = (size_t)nB*64 + lane;
    m.shA = Hh2[iA]; m.slA = Hl2[iA];
    m.shB = Hh2[iB]; m.slB = Hl2[iB];
}

__device__ __forceinline__ void load_jj(int* jjA, int* jjB, const MetaA& m,
                                        const int* __restrict__ csr){
    int jmA = m.j0A + m.cA - 1;
    int jmB = m.j0B + m.cB - 1;
    #pragma unroll
    for(int t=0;t<8;t++){
        int ia = m.j0A + t; ia = ia > jmA ? jmA : ia;
        int ib = m.j0B + t; ib = ib > jmB ? jmB : ib;
        jjA[t] = csr[ia] & (N_NODES-1);
        jjB[t] = csr[ib] & (N_NODES-1);
    }
}

__device__ __forceinline__ void agg_step(
        const MetaA& cur, const int* jjA, const int* jjB, int ii,
        MetaA* m2, int n2,
        int* jj1A, int* jj1B, const MetaA* m1,
        int base16, int lane,
        const uint32* __restrict__ Hh2, const uint32* __restrict__ Hl2,
        const float* __restrict__ dinv, const int* __restrict__ rowptr,
        const int* __restrict__ csr,
        uint32* __restrict__ AhL, uint32* __restrict__ AlL){
    uint32 rrA[8], rrB[8];
    float  wwA[8], wwB[8];
    #pragma unroll
    for(int t=0;t<8;t++){
        wwA[t] = (t < cur.cA) ? dinv[jjA[t]] : 0.f;
        rrA[t] = Hh2[(size_t)jjA[t]*64 + lane];
        wwB[t] = (t < cur.cB) ? dinv[jjB[t]] : 0.f;
        rrB[t] = Hh2[(size_t)jjB[t]*64 + lane];
    }
    if(m2) load_metaA(*m2, n2, lane, rowptr, dinv, Hh2, Hl2);
    if(m1) load_jj(jj1A, jj1B, *m1, csr);
    float axA = (unpack_even(cur.shA) + unpack_even(cur.slA)) * cur.dnA;
    float ayA = (unpack_odd(cur.shA)  + unpack_odd(cur.slA))  * cur.dnA;
    float axB = (unpack_even(cur.shB) + unpack_even(cur.slB)) * cur.dnB;
    float ayB = (unpack_odd(cur.shB)  + unpack_odd(cur.slB))  * cur.dnB;
    #pragma unroll
    for(int t=0;t<8;t++){
        axA = fmaf(unpack_even(rrA[t]), wwA[t], axA);
        ayA = fmaf(unpack_odd(rrA[t]),  wwA[t], ayA);
        axB = fmaf(unpack_even(rrB[t]), wwB[t], axB);
        ayB = fmaf(unpack_odd(rrB[t]),  wwB[t], ayB);
    }
    int nb = cur.cA > cur.cB ? cur.cA : cur.cB;
    if(nb > 8){
        int jmA = cur.j0A + cur.cA - 1;
        int jmB = cur.j0B + cur.cB - 1;
        for(int j=8; j<nb; j+=8){
            int jja[8], jjb[8]; float wa[8], wb[8]; uint32 ra[8], rb[8];
            #pragma unroll
            for(int t=0;t<8;t++){
                int ia = cur.j0A + j + t; ia = ia > jmA ? jmA : ia;
                int ib = cur.j0B + j + t; ib = ib > jmB ? jmB : ib;
                jja[t] = csr[ia] & (N_NODES-1);
                jjb[t] = csr[ib] & (N_NODES-1);
            }
            #pragma unroll
            for(int t=0;t<8;t++){
                wa[t] = (j + t < cur.cA) ? dinv[jja[t]] : 0.f;
                ra[t] = Hh2[(size_t)jja[t]*64 + lane];
                wb[t] = (j + t < cur.cB) ? dinv[jjb[t]] : 0.f;
                rb[t] = Hh2[(size_t)jjb[t]*64 + lane];
            }
            #pragma unroll
            for(int t=0;t<8;t++){
                axA = fmaf(unpack_even(ra[t]), wa[t], axA);
                ayA = fmaf(unpack_odd(ra[t]),  wa[t], ayA);
                axB = fmaf(unpack_even(rb[t]), wb[t], axB);
                ayB = fmaf(unpack_odd(rb[t]),  wb[t], ayB);
            }
        }
    }
    axA *= cur.dnA; ayA *= cur.dnA;
    axB *= cur.dnB; ayB *= cur.dnB;
    int rowA = base16 + ii, rowB = rowA + 8;
    uint32 hxA = bfbits(axA), hyA = bfbits(ayA);
    AhL[rowA*68 + lane] = hxA | (hyA<<16);
    AlL[rowA*68 + lane] = pack2(axA - __uint_as_float(hxA<<16),
                                ayA - __uint_as_float(hyA<<16));
    uint32 hxB = bfbits(axB), hyB = bfbits(ayB);
    AhL[rowB*68 + lane] = hxB | (hyB<<16);
    AlL[rowB*68 + lane] = pack2(axB - __uint_as_float(hxB<<16),
                                ayB - __uint_as_float(hyB<<16));
}

__global__ __launch_bounds__(512, 4)
void k_layer(const __bf16* __restrict__ curHh, const __bf16* __restrict__ curHl,
             const float* __restrict__ dinv, const int* __restrict__ rowptr,
             const int* __restrict__ csr,
             const __bf16* __restrict__ Bth, const __bf16* __restrict__ Btl,
             const float* __restrict__ bias, const float* __restrict__ gamma,
             const float* __restrict__ beta,
             uint32* __restrict__ outHh2, uint32* __restrict__ outHl2, int residual){
    __shared__ uint32 smem[8*32*68];              // 69632 B; A-region then reused as staging
    uint32* AhL = smem;
    uint32* AlL = smem + 128*68;
    int tid  = threadIdx.x;
    int wave = __builtin_amdgcn_readfirstlane(tid >> 6);
    int lane = tid & 63;
    int rbase = blockIdx.x * 128;
    int base16 = wave*16;
    const uint32* Hh2 = (const uint32*)curHh;
    const uint32* Hl2 = (const uint32*)curHl;

    // ---- stage 1: pipelined aggregation, 16 nodes/wave as 8 pairs ----
    {
        MetaA m0, m1, m2;
        int jj0A[8], jj0B[8], jj1A[8], jj1B[8];
        int nb0 = rbase + base16;
        load_metaA(m0, nb0+0, lane, rowptr, dinv, Hh2, Hl2);
        load_metaA(m1, nb0+1, lane, rowptr, dinv, Hh2, Hl2);
        load_jj(jj0A, jj0B, m0, csr);
        agg_step(m0, jj0A, jj0B, 0, &m2, nb0+2, jj1A, jj1B, &m1,
                 base16, lane, Hh2, Hl2, dinv, rowptr, csr, AhL, AlL);
        agg_step(m1, jj1A, jj1B, 1, &m0, nb0+3, jj0A, jj0B, &m2,
                 base16, lane, Hh2, Hl2, dinv, rowptr, csr, AhL, AlL);
        agg_step(m2, jj0A, jj0B, 2, &m1, nb0+4, jj1A, jj1B, &m0,
                 base16, lane, Hh2, Hl2, dinv, rowptr, csr, AhL, AlL);
        agg_step(m0, jj1A, jj1B, 3, &m2, nb0+5, jj0A, jj0B, &m1,
                 base16, lane, Hh2, Hl2, dinv, rowptr, csr, AhL, AlL);
        agg_step(m1, jj0A, jj0B, 4, &m0, nb0+6, jj1A, jj1B, &m2,
                 base16, lane, Hh2, Hl2, dinv, rowptr, csr, AhL, AlL);
        agg_step(m2, jj1A, jj1B, 5, &m1, nb0+7, jj0A, jj0B, &m0,
                 base16, lane, Hh2, Hl2, dinv, rowptr, csr, AhL, AlL);
        agg_step(m0, jj0A, jj0B, 6, nullptr, 0, jj1A, jj1B, &m1,
                 base16, lane, Hh2, Hl2, dinv, rowptr, csr, AhL, AlL);
        agg_step(m1, jj1A, jj1B, 7, nullptr, 0, nullptr, nullptr, nullptr,
                 base16, lane, Hh2, Hl2, dinv, rowptr, csr, AhL, AlL);
    }
    __syncthreads();

    int lr = lane & 15, lq = lane >> 4;
    int wr = wave & 3, wc = wave >> 2;
    int r0 = wr*32;
    bf16x8 A0h[4], A0l[4], A1h[4], A1l[4];
    #pragma unroll
    for(int ks=0;ks<4;ks++){
        int u0 = (r0 + lr)*68 + lq*4 + ks*16;
        int u1 = (r0 + 16 + lr)*68 + lq*4 + ks*16;
        A0h[ks] = __builtin_bit_cast(bf16x8, *(const u32x4*)(AhL + u0));
        A0l[ks] = __builtin_bit_cast(bf16x8, *(const u32x4*)(AlL + u0));
        A1h[ks] = __builtin_bit_cast(bf16x8, *(const u32x4*)(AhL + u1));
        A1l[ks] = __builtin_bit_cast(bf16x8, *(const u32x4*)(AlL + u1));
    }
    __syncthreads();

    float* stg = (float*)smem + wave*(32*68);
    const f32x4 zero4 = {0.f,0.f,0.f,0.f};
    #pragma unroll
    for(int cc=0; cc<4; cc++){
        int col = wc*64 + cc*16 + lr;
        f32x4 a0 = zero4, a1 = zero4;
        #pragma unroll
        for(int ks=0;ks<4;ks++){
            bf16x8 Bh = *(const bf16x8*)(Bth + col*H_DIM + ks*32 + lq*8);
            bf16x8 Bl = *(const bf16x8*)(Btl + col*H_DIM + ks*32 + lq*8);
            a0 = __builtin_amdgcn_mfma_f32_16x16x32_bf16(A0h[ks], Bh, a0, 0,0,0);
            a0 = __builtin_amdgcn_mfma_f32_16x16x32_bf16(A0l[ks], Bh, a0, 0,0,0);
            a0 = __builtin_amdgcn_mfma_f32_16x16x32_bf16(A0h[ks], Bl, a0, 0,0,0);
            a1 = __builtin_amdgcn_mfma_f32_16x16x32_bf16(A1h[ks], Bh, a1, 0,0,0);
            a1 = __builtin_amdgcn_mfma_f32_16x16x32_bf16(A1l[ks], Bh, a1, 0,0,0);
            a1 = __builtin_amdgcn_mfma_f32_16x16x32_bf16(A1h[ks], Bl, a1, 0,0,0);
        }
        #pragma unroll
        for(int r=0;r<4;r++){
            stg[(lq*4+r)*68 + cc*16 + lr]    = a0[r];
            stg[(16+lq*4+r)*68 + cc*16 + lr] = a1[r];
        }
    }

    int orow = lane >> 3;
    int oq   = lane & 7;
    int cg = wc*64 + oq*8;
    float bb[8], gg[8], tt[8];
    *(float4*)&bb[0] = *(const float4*)(bias + cg);
    *(float4*)&bb[4] = *(const float4*)(bias + cg + 4);
    *(float4*)&gg[0] = *(const float4*)(gamma + cg);
    *(float4*)&gg[4] = *(const float4*)(gamma + cg + 4);
    *(float4*)&tt[0] = *(const float4*)(beta + cg);
    *(float4*)&tt[4] = *(const float4*)(beta + cg + 4);
    #pragma unroll
    for(int p=0;p<8;p++) gg[p] *= BN_SCALE;
    #pragma unroll
    for(int i=0;i<4;i++){
        int row = i*8 + orow;
        float v[8];
        *(float4*)&v[0] = *(float4*)&stg[row*68 + oq*8];
        *(float4*)&v[4] = *(float4*)&stg[row*68 + oq*8 + 4];
        size_t oidx = (size_t)(rbase + r0 + row)*64 + (cg>>1);
        uint4 oldh = {0,0,0,0}, oldl = {0,0,0,0};
        if(residual){
            oldh = *(const uint4*)(Hh2 + oidx);
            oldl = *(const uint4*)(Hl2 + oidx);
        }
        uint32 ohv[4] = {oldh.x,oldh.y,oldh.z,oldh.w};
        uint32 olv[4] = {oldl.x,oldl.y,oldl.z,oldl.w};
        uint32 oh[4], ol[4];
        #pragma unroll
        for(int p=0;p<4;p++){
            float ve = fmaxf(fmaf(v[2*p]   + bb[2*p],   gg[2*p],   tt[2*p]),   0.f);
            float vo = fmaxf(fmaf(v[2*p+1] + bb[2*p+1], gg[2*p+1], tt[2*p+1]), 0.f);
            if(residual){
                ve += unpack_even(ohv[p]) + unpack_even(olv[p]);
                vo += unpack_odd(ohv[p])  + unpack_odd(olv[p]);
            }
            uint32 he = bfbits(ve), ho = bfbits(vo);
            oh[p] = he | (ho<<16);
            float le = ve - __uint_as_float(he<<16);
            float lo = vo - __uint_as_float(ho<<16);
            ol[p] = pack2(le, lo);
        }
        *(uint4*)(outHh2 + oidx) = make_uint4(oh[0],oh[1],oh[2],oh[3]);
        *(uint4*)(outHl2 + oidx) = make_uint4(ol[0],ol[1],ol[2],ol[3]);
    }
}

// ---------------- gene GEMM via MFMA, fused A-split, atomic accumulation into g1acc ----------------

__global__ __launch_bounds__(256)
void k_gemm_gf_mfma(const float* __restrict__ Agf,
                    const __bf16* __restrict__ Bth, const __bf16* __restrict__ Btl,
                    float* __restrict__ g1acc){
    int rt = blockIdx.x & 31;       // 32 row tiles of 64
    int sp = blockIdx.x >> 5;       // NSPLIT k-splits
    int ks0 = (sp*138) >> 5, ks1 = ((sp+1)*138) >> 5;
    int wave = threadIdx.x >> 6, lane = threadIdx.x & 63;
    int lr = lane & 15, lq = lane >> 4;
    int rbase = rt*64 + (wave & 1)*32;
    int cbase = (wave >> 1)*128;
    const f32x4 zero4 = {0.f,0.f,0.f,0.f};
    f32x4 acc[8][2];
    #pragma unroll
    for(int ct=0;ct<8;ct++){ acc[ct][0] = zero4; acc[ct][1] = zero4; }
    for(int ks=ks0; ks<ks1; ks++){
        int kc = ks*32;
        const float* ar0 = Agf + (size_t)(rbase + lr)*GF_DIM + kc + lq*8;
        const float* ar1 = ar0 + (size_t)16*GF_DIM;
        bf16x8 A0h, A0l, A1h, A1l;
        if(kc + 32 <= GF_DIM){
            #pragma unroll
            for(int t=0;t<8;t++){
                __bf16 h, l;
                split2(ar0[t], h, l); A0h[t] = h; A0l[t] = l;
                split2(ar1[t], h, l); A1h[t] = h; A1l[t] = l;
            }
        } else {
            #pragma unroll
            for(int t=0;t<8;t++){
                int k = kc + lq*8 + t;
                float v0 = 0.f, v1 = 0.f;
                if(k < GF_DIM){ v0 = ar0[t]; v1 = ar1[t]; }
                __bf16 h, l;
                split2(v0, h, l); A0h[t] = h; A0l[t] = l;
                split2(v1, h, l); A1h[t] = h; A1l[t] = l;
            }
        }
        #pragma unroll
        for(int ct=0;ct<8;ct++){
            size_t bo = (size_t)(cbase + ct*16 + lr)*GF_PAD + kc + lq*8;
            bf16x8 Bh = *(const bf16x8*)(Bth + bo);
            bf16x8 Bl = *(const bf16x8*)(Btl + bo);
            acc[ct][0] = __builtin_amdgcn_mfma_f32_16x16x32_bf16(A0h, Bh, acc[ct][0], 0,0,0);
            acc[ct][0] = __builtin_amdgcn_mfma_f32_16x16x32_bf16(A0l, Bh, acc[ct][0], 0,0,0);
            acc[ct][0] = __builtin_amdgcn_mfma_f32_16x16x32_bf16(A0h, Bl, acc[ct][0], 0,0,0);
            acc[ct][1] = __builtin_amdgcn_mfma_f32_16x16x32_bf16(A1h, Bh, acc[ct][1], 0,0,0);
            acc[ct][1] = __builtin_amdgcn_mfma_f32_16x16x32_bf16(A1l, Bh, acc[ct][1], 0,0,0);
            acc[ct][1] = __builtin_amdgcn_mfma_f32_16x16x32_bf16(A1h, Bl, acc[ct][1], 0,0,0);
        }
    }
    #pragma unroll
    for(int ct=0;ct<8;ct++)
        #pragma unroll
        for(int s=0;s<2;s++)
            #pragma unroll
            for(int r=0;r<4;r++)
                atomicAdd(&g1acc[(size_t)(rbase + s*16 + lq*4 + r)*256 + cbase + ct*16 + lr],
                          acc[ct][s][r]);
}

// ---------------- FUSED head v4: 8 graphs/block, LDS weights; g1 epilogue folded in ----

__device__ __forceinline__ void load_w4(const float* __restrict__ W, int off, int tid,
                                        float4* t){
    const float4* s = (const float4*)(W + off);
    t[0] = s[tid];
    t[1] = s[tid + 512];
    t[2] = s[tid + 1024];
    t[3] = s[tid + 1536];
}
__device__ __forceinline__ void write_w4(float* sW, int tid, const float4* t){
    float4* d = (float4*)sW;
    d[tid]        = t[0];
    d[tid + 512]  = t[1];
    d[tid + 1024] = t[2];
    d[tid + 1536] = t[3];
}

__device__ __forceinline__ void dense_stage128(
        const float* __restrict__ W, int nck, const float* sA, int lda,
        float* sO, int ldo, float* sW, int tid, int c, int ga, int gb,
        float bias_c, float gsc, float bsh, int do_relu){
    float4 t[4];
    load_w4(W, 0, tid, t);
    write_w4(sW, tid, t);
    __syncthreads();
    float a0 = bias_c, a1 = bias_c;
    for(int ck=0; ck<nck; ck++){
        if(ck+1 < nck) load_w4(W, (ck+1)*8192, tid, t);
        const float* aga = sA + ga*lda + ck*64;
        const float* agb = sA + gb*lda + ck*64;
        #pragma unroll
        for(int k=0;k<64;k++){
            float w = sW[k*128 + c];
            a0 = fmaf(aga[k], w, a0);
            a1 = fmaf(agb[k], w, a1);
        }
        __syncthreads();
        if(ck+1 < nck){ write_w4(sW, tid, t); __syncthreads(); }
    }
    a0 = fmaf(a0, gsc, bsh);
    a1 = fmaf(a1, gsc, bsh);
    if(do_relu){ a0 = fmaxf(a0, 0.f); a1 = fmaxf(a1, 0.f); }
    sO[ga*ldo + c] = a0;
    sO[gb*ldo + c] = a1;
}

__global__ __launch_bounds__(512)
void k_head(const uint32* __restrict__ Hh2, const uint32* __restrict__ Hl2,
            const float* __restrict__ g1acc,
            const float* __restrict__ bge1, const float* __restrict__ g_g,
            const float* __restrict__ g_b,
            const float* __restrict__ Wd1, const float* __restrict__ bd1,
            const float* __restrict__ Wd2, const float* __restrict__ bd2,
            const float* __restrict__ Wge2, const float* __restrict__ bge2,
            const float* __restrict__ Wh1, const float* __restrict__ bh1,
            const float* __restrict__ h_g, const float* __restrict__ h_b,
            const float* __restrict__ Wh2, const float* __restrict__ bh2,
            const float* __restrict__ Wh3, const float* __restrict__ bh3,
            float* __restrict__ out){
    __shared__ float sPool[8][256];
    __shared__ float sG1[8][256];
    __shared__ float sT1[8][128];
    __shared__ float sComb[8][256];
    __shared__ float sZ[8][128];
    __shared__ float sZ2[8][64];
    __shared__ float sW[8192];          // 32 KB weight chunk
    int tid = threadIdx.x;
    int wave = tid >> 6, lane = tid & 63;
    int g0 = blockIdx.x*8;
    // g1 = relu((g1acc + bge1) * g_g*BN_SCALE + g_b), folded into the LDS load
    {
        int idx = tid*4;                 // 0..2047
        int g = idx >> 8, c = idx & 255;
        float4 a  = *(const float4*)&g1acc[(size_t)(g0+g)*256 + c];
        float4 b  = *(const float4*)&bge1[c];
        float4 gm = *(const float4*)&g_g[c];
        float4 bt = *(const float4*)&g_b[c];
        sG1[g][c+0] = fmaxf(fmaf(a.x + b.x, gm.x*BN_SCALE, bt.x), 0.f);
        sG1[g][c+1] = fmaxf(fmaf(a.y + b.y, gm.y*BN_SCALE, bt.y), 0.f);
        sG1[g][c+2] = fmaxf(fmaf(a.z + b.z, gm.z*BN_SCALE, bt.z), 0.f);
        sG1[g][c+3] = fmaxf(fmaf(a.w + b.w, gm.w*BN_SCALE, bt.w), 0.f);
    }
    {
        size_t base = (size_t)(g0+wave)*4096 + lane;
        float se = 0.f, so = 0.f, me = -3.4e38f, mo = -3.4e38f;
        #pragma unroll 8
        for(int r=0;r<64;r++){
            uint32 h = Hh2[base + r*64];
            uint32 l = Hl2[base + r*64];
            float ve = unpack_even(h) + unpack_even(l);
            float vo = unpack_odd(h)  + unpack_odd(l);
            se += ve; so += vo;
            me = fmaxf(me, ve); mo = fmaxf(mo, vo);
        }
        sPool[wave][2*lane]       = se*(1.f/64.f);
        sPool[wave][2*lane+1]     = so*(1.f/64.f);
        sPool[wave][128+2*lane]   = me;
        sPool[wave][128+2*lane+1] = mo;
    }
    __syncthreads();
    int c = tid & 127, q = tid >> 7;     // q in 0..3 -> graphs 2q, 2q+1
    int ga = 2*q, gb = 2*q + 1;
    dense_stage128(Wd1, 4, &sPool[0][0], 256, &sT1[0][0], 128, sW, tid, c, ga, gb,
                   bd1[c], 1.f, 0.f, 1);
    dense_stage128(Wd2, 2, &sT1[0][0], 128, &sComb[0][0], 256, sW, tid, c, ga, gb,
                   bd2[c], 1.f, 0.f, 0);
    dense_stage128(Wge2, 4, &sG1[0][0], 256, &sComb[0][0] + 128, 256, sW, tid, c, ga, gb,
                   bge2[c], 1.f, 0.f, 1);
    dense_stage128(Wh1, 4, &sComb[0][0], 256, &sZ[0][0], 128, sW, tid, c, ga, gb,
                   bh1[c], h_g[c]*BN_SCALE, h_b[c], 1);
    {
        float4 t[4];
        load_w4(Wh2, 0, tid, t);
        write_w4(sW, tid, t);
        __syncthreads();
        int c2 = tid & 63, q2 = tid >> 6;     // q2 = graph
        float a = bh2[c2];
        #pragma unroll
        for(int k=0;k<128;k++)
            a = fmaf(sZ[q2][k], sW[k*64 + c2], a);
        sZ2[q2][c2] = fmaxf(a, 0.f);
    }
    __syncthreads();
    {
        float v = sZ2[wave][lane] * Wh3[lane];
        #pragma unroll
        for(int off=32; off; off>>=1) v += __shfl_down(v, off);
        if(lane == 0) out[g0 + wave] = v + bh3[0];
    }
}

// ---------------- launch ----------------

extern "C" void kernel_launch(void* const* d_in, const int* in_sizes, int n_in,
                              void* d_out, int out_size, void* d_ws, size_t ws_size,
                              hipStream_t stream){
    (void)in_sizes; (void)n_in; (void)out_size; (void)ws_size;
    const float* x    = (const float*)d_in[0];
    const float* gf   = (const float*)d_in[1];
    const int*   ei   = (const int*)  d_in[2];
    const float* W_emb= (const float*)d_in[4];
    const float* b_emb= (const float*)d_in[5];
    const float* Wg   = (const float*)d_in[6];
    const float* bg   = (const float*)d_in[7];
    const float* bn_g = (const float*)d_in[8];
    const float* bn_b = (const float*)d_in[9];
    const float* Wd1  = (const float*)d_in[10];
    const float* bd1  = (const float*)d_in[11];
    const float* Wd2  = (const float*)d_in[12];
    const float* bd2  = (const float*)d_in[13];
    const float* Wge1 = (const float*)d_in[14];
    const float* bge1 = (const float*)d_in[15];
    const float* g_g  = (const float*)d_in[16];
    const float* g_b  = (const float*)d_in[17];
    const float* Wge2 = (const float*)d_in[18];
    const float* bge2 = (const float*)d_in[19];
    const float* Wh1  = (const float*)d_in[20];
    const float* bh1  = (const float*)d_in[21];
    const float* h_g  = (const float*)d_in[22];
    const float* h_b  = (const float*)d_in[23];
    const float* Wh2  = (const float*)d_in[24];
    const float* bh2  = (const float*)d_in[25];
    const float* Wh3  = (const float*)d_in[26];
    const float* bh3  = (const float*)d_in[27];
    float* outp = (float*)d_out;

    char* base = (char*)d_ws;
    __bf16* Hh = (__bf16*)base;                              // 32 MiB (ping)
    __bf16* Hl = (__bf16*)(base + (32u<<20));                // 32 MiB
    __bf16* Ph = (__bf16*)(base + (64u<<20));                // 32 MiB (pong)
    __bf16* Pl = (__bf16*)(base + (96u<<20));                // 32 MiB
    // gene weight splits live in Ph region (dead until k_layer i=0 writes it, after gemm)
    __bf16* wge_th = (__bf16*)(base + (64u<<20));            // 2,260,992 B
    __bf16* wge_tl = (__bf16*)(base + (64u<<20) + 2260992);  // ends < 69 MiB
    // tail:
    char* T = base + (128u<<20);
    float* g1acc = (float*)T;                                // 2 MiB (atomic accumulator)
    int* counts = (int*)(g1acc + B_GR*256);
    int* rowptr = counts + N_NODES;
    int* cursor = rowptr + (N_NODES+1);
    int* csr    = cursor + N_NODES;
    int* bsums  = csr + E_EDGES;
    float* dinv = (float*)(bsums + 128);
    __bf16* wg_th = (__bf16*)(dinv + N_NODES);               // 3*16384
    __bf16* wg_tl = wg_th + 3*16384;
    __bf16* we_th = wg_tl + 3*16384;                         // 128*32
    __bf16* we_tl = we_th + 128*32;

    const int* src = ei;
    const int* dst = ei + E_EDGES;

    // weights split (Wge1 tile-transpose + Wg + Wemb in one launch)
    k_split_weights<<<484, 256, 0, stream>>>(Wge1, wge_th, wge_tl, Wg, wg_th, wg_tl,
                                             W_emb, we_th, we_tl);

    // zero counts + g1acc in one launch
    k_zero2<<<(N_NODES + B_GR*256 + 255)/256, 256, 0, stream>>>(counts, N_NODES,
                                                                g1acc, B_GR*256);

    // gene GEMM (atomic accumulation into g1acc; epilogue folded into k_head)
    k_gemm_gf_mfma<<<32*NSPLIT, 256, 0, stream>>>(gf, wge_th, wge_tl, g1acc);

    // graph prep
    k_count<<<E_EDGES/256, 256, 0, stream>>>(dst, counts);
    k_scan1<<<128, 1024, 0, stream>>>(counts, bsums);
    k_scan2<<<1, 128, 0, stream>>>(bsums);
    k_scan3<<<128, 1024, 0, stream>>>(counts, bsums, rowptr, dinv, cursor);
    k_fill <<<E_EDGES/256, 256, 0, stream>>>(src, dst, cursor, csr);

    // embedding (fused x split)
    k_emb_mfma<<<N_NODES/128, 256, 0, stream>>>(x, we_th, we_tl, b_emb,
                                                (uint32*)Hh, (uint32*)Hl);

    // 3 fused GCN layers, ping-pong (Hh,Hl) <-> (Ph,Pl)
    uint32 *curh = (uint32*)Hh, *curl = (uint32*)Hl;
    uint32 *outh = (uint32*)Ph, *outl = (uint32*)Pl;
    for(int i=0;i<3;i++){
        k_layer<<<N_NODES/128, 512, 0, stream>>>((const __bf16*)curh, (const __bf16*)curl,
                                                 dinv, rowptr, csr,
                                                 wg_th + i*16384, wg_tl + i*16384,
                                                 bg + i*H_DIM, bn_g + i*H_DIM, bn_b + i*H_DIM,
                                                 outh, outl, i > 0);
        uint32* th = curh; curh = outh; outh = th;
        uint32* tl = curl; curl = outl; outl = tl;
    }

    // fused head v4 (g1 epilogue folded); final H is in (curh, curl)
    k_head<<<B_GR/8, 512, 0, stream>>>(curh, curl, g1acc, bge1, g_g, g_b,
                                       Wd1, bd1, Wd2, bd2, Wge2, bge2,
                                       Wh1, bh1, h_g, h_b, Wh2, bh2, Wh3, bh3, outp);
}

// Round 11
// 548.486 us; speedup vs baseline: 1.0628x; 1.0628x over previous
//
#include <hip/hip_runtime.h>

#define N_NODES 131072
#define E_EDGES 524288
#define B_GR    2048
#define H_DIM   128
#define NF_DIM  30
#define GF_DIM  4415
#define GF_PAD  4416            // 138*32 = 69*64
#define BN_SCALE 0.9999950000374997f   // 1/sqrt(1+1e-5)
#define NSPLIT  16              // gene GEMM k-splits

typedef __bf16 bf16x8 __attribute__((ext_vector_type(8)));
typedef float  f32x4  __attribute__((ext_vector_type(4)));
typedef unsigned int uint32;
typedef uint32 u32x4 __attribute__((ext_vector_type(4)));

__device__ __forceinline__ void split2(float x, __bf16& hi, __bf16& lo){
    hi = (__bf16)x;
    lo = (__bf16)(x - (float)hi);
}
__device__ __forceinline__ uint32 bfbits(float x){
    __bf16 h = (__bf16)x;
    return (uint32)__builtin_bit_cast(unsigned short, h);
}
// packed uint32: low 16 bits = even col, high 16 bits = odd col
__device__ __forceinline__ float unpack_even(uint32 u){ return __uint_as_float(u<<16); }
__device__ __forceinline__ float unpack_odd (uint32 u){ return __uint_as_float(u & 0xffff0000u); }
__device__ __forceinline__ uint32 pack2(float e, float o){ return bfbits(e) | (bfbits(o)<<16); }

// ---------------- graph prep ----------------

__global__ void k_zero_int(int* __restrict__ p, int n){
    int i = blockIdx.x*256 + threadIdx.x;
    if(i < n) p[i] = 0;
}

__global__ void k_count(const int* __restrict__ dst, int* __restrict__ counts){
    int e = blockIdx.x*256 + threadIdx.x;
    if(e < E_EDGES) atomicAdd(&counts[dst[e]], 1);
}

__global__ void k_scan1(int* __restrict__ counts, int* __restrict__ bsums){
    __shared__ int s[1024];
    int t = threadIdx.x;
    int gi = blockIdx.x*1024 + t;
    int v = counts[gi];
    s[t] = v; __syncthreads();
    for(int off=1; off<1024; off<<=1){
        int x = (t>=off) ? s[t-off] : 0;
        __syncthreads();
        s[t] += x;
        __syncthreads();
    }
    counts[gi] = s[t] - v;
    if(t == 1023) bsums[blockIdx.x] = s[t];
}

__global__ void k_scan2(int* __restrict__ bsums){
    __shared__ int s[128];
    int t = threadIdx.x;
    int v = bsums[t]; s[t] = v; __syncthreads();
    for(int off=1; off<128; off<<=1){
        int x = (t>=off) ? s[t-off] : 0;
        __syncthreads();
        s[t] += x;
        __syncthreads();
    }
    bsums[t] = s[t] - v;
}

// merged: rowptr + dinv + cursor (counts is read-only here; cursor is a separate buffer)
__global__ void k_scan3(const int* __restrict__ counts, const int* __restrict__ bsums,
                        int* __restrict__ rowptr, float* __restrict__ dinv,
                        int* __restrict__ cursor){
    int i = blockIdx.x*1024 + threadIdx.x;
    int r0 = counts[i] + bsums[blockIdx.x];
    int r1;
    if(i == N_NODES-1){
        r1 = E_EDGES;
        rowptr[N_NODES] = E_EDGES;
    } else {
        int ip = i + 1;
        int nb = (threadIdx.x == 1023) ? blockIdx.x + 1 : blockIdx.x;
        r1 = counts[ip] + bsums[nb];
    }
    rowptr[i] = r0;
    dinv[i] = rsqrtf((float)(r1 - r0) + 1.0f);
    cursor[i] = r0;
}

__global__ void k_fill(const int* __restrict__ src, const int* __restrict__ dst,
                       int* __restrict__ cursor, int* __restrict__ csr){
    int e = blockIdx.x*256 + threadIdx.x;
    if(e < E_EDGES){
        int p = atomicAdd(&cursor[dst[e]], 1);
        csr[p] = src[e];
    }
}

// ---------------- combined weight split: Wge1 (frag-linear) + Wg + Wemb ----------------
// gene-B frag-linear layout: tile (ct=c>>4, kt=k>>5) -> base (ct*138 + kt)*512,
// within-tile offset (c&15)*32 + (k&31). A wave's fragment load = 1 KB contiguous.

__global__ void k_split_weights(const float* __restrict__ Wge1, __bf16* __restrict__ wth,
                                __bf16* __restrict__ wtl,
                                const float* __restrict__ Wg, __bf16* __restrict__ gth,
                                __bf16* __restrict__ gtl,
                                const float* __restrict__ Wemb, __bf16* __restrict__ eth,
                                __bf16* __restrict__ etl){
    __shared__ float sTile[64][65];
    unsigned bid = blockIdx.x;
    int tid = threadIdx.x;
    if(bid < 276u){
        // Wge1: 64(k) x 64(c) tile; coalesced reads; frag-linear writes (32-elem dense runs)
        int kt = bid % 69u, ct = bid / 69u;
        int k0 = kt*64, c0 = ct*64;
        #pragma unroll
        for(int i=0;i<16;i++){
            int idx = i*256 + tid;
            int kk = idx >> 6, cc = idx & 63;
            int k = k0 + kk;
            sTile[kk][cc] = (k < GF_DIM) ? Wge1[(size_t)k*256 + c0 + cc] : 0.f;
        }
        __syncthreads();
        #pragma unroll
        for(int i=0;i<16;i++){
            int idx = i*256 + tid;
            int cc = idx >> 6, kk = idx & 63;
            float v = sTile[kk][cc];
            int c = c0 + cc, k = k0 + kk;
            size_t o = ((size_t)(c >> 4)*138 + (k >> 5))*512 + (c & 15)*32 + (k & 31);
            split2(v, wth[o], wtl[o]);
        }
    } else if(bid < 276u + 192u){
        int idx = (bid - 276u)*256 + tid;            // 3*128*128
        int l = idx >> 14, i = idx & 16383;
        int k = i >> 7, c = i & 127;
        float v = Wg[idx];
        int o = (l << 14) + (c << 7) + k;            // transposed: [l][c][k]
        split2(v, gth[o], gtl[o]);
    } else {
        int idx = (bid - 468u)*256 + tid;            // 128*32  (c-major, k padded)
        int c = idx >> 5, k = idx & 31;
        float v = (k < NF_DIM) ? Wemb[k*H_DIM + c] : 0.f;
        split2(v, eth[idx], etl[idx]);
    }
}

// ---------------- embedding via MFMA (fused x split):  relu(x @ W_emb + b) ----------------

__global__ __launch_bounds__(256)
void k_emb_mfma(const float* __restrict__ x,
                const __bf16* __restrict__ wth, const __bf16* __restrict__ wtl,
                const float* __restrict__ bias, uint32* __restrict__ Hh2,
                uint32* __restrict__ Hl2){
    __shared__ float sT[4][32*68];
    int wave = threadIdx.x >> 6, lane = threadIdx.x & 63;
    int lr = lane & 15, lq = lane >> 4;
    int rbase = blockIdx.x*128 + wave*32;
    const f32x4 zero4 = {0.f,0.f,0.f,0.f};
    const float* xr0 = x + (size_t)(rbase + lr)*NF_DIM;
    const float* xr1 = x + (size_t)(rbase + 16 + lr)*NF_DIM;
    bf16x8 A0h, A0l, A1h, A1l;
    #pragma unroll
    for(int t=0;t<8;t++){
        int k = lq*8 + t;
        float v0 = (k < NF_DIM) ? xr0[k] : 0.f;
        float v1 = (k < NF_DIM) ? xr1[k] : 0.f;
        __bf16 h, l;
        split2(v0, h, l); A0h[t] = h; A0l[t] = l;
        split2(v1, h, l); A1h[t] = h; A1l[t] = l;
    }
    int orow = lane >> 3;          // 0..7
    int oq   = lane & 7;           // 0..7
    float* sW = sT[wave];
    for(int ph=0; ph<2; ph++){
        #pragma unroll
        for(int cc=0; cc<4; cc++){
            int col = (ph*4+cc)*16 + lr;
            bf16x8 Bh = *(const bf16x8*)(wth + col*32 + lq*8);
            bf16x8 Bl = *(const bf16x8*)(wtl + col*32 + lq*8);
            f32x4 a0 = zero4, a1 = zero4;
            a0 = __builtin_amdgcn_mfma_f32_16x16x32_bf16(A0h, Bh, a0, 0,0,0);
            a0 = __builtin_amdgcn_mfma_f32_16x16x32_bf16(A0l, Bh, a0, 0,0,0);
            a0 = __builtin_amdgcn_mfma_f32_16x16x32_bf16(A0h, Bl, a0, 0,0,0);
            a1 = __builtin_amdgcn_mfma_f32_16x16x32_bf16(A1h, Bh, a1, 0,0,0);
            a1 = __builtin_amdgcn_mfma_f32_16x16x32_bf16(A1l, Bh, a1, 0,0,0);
            a1 = __builtin_amdgcn_mfma_f32_16x16x32_bf16(A1h, Bl, a1, 0,0,0);
            #pragma unroll
            for(int r=0;r<4;r++){
                sW[(lq*4+r)*68 + cc*16 + lr]    = a0[r];
                sW[(16+lq*4+r)*68 + cc*16 + lr] = a1[r];
            }
        }
        __syncthreads();
        int cg = ph*64 + oq*8;
        float bb[8];
        *(float4*)&bb[0] = *(const float4*)(bias + cg);
        *(float4*)&bb[4] = *(const float4*)(bias + cg + 4);
        #pragma unroll
        for(int i=0;i<4;i++){
            int row = i*8 + orow;
            float v[8];
            *(float4*)&v[0] = *(float4*)&sW[row*68 + oq*8];
            *(float4*)&v[4] = *(float4*)&sW[row*68 + oq*8 + 4];
            uint32 oh[4], ol[4];
            #pragma unroll
            for(int p=0;p<4;p++){
                float ve = fmaxf(v[2*p]   + bb[2*p],   0.f);
                float vo = fmaxf(v[2*p+1] + bb[2*p+1], 0.f);
                uint32 he = bfbits(ve), ho = bfbits(vo);
                oh[p] = he | (ho<<16);
                float le = ve - __uint_as_float(he<<16);
                float lo = vo - __uint_as_float(ho<<16);
                ol[p] = pack2(le, lo);
            }
            size_t oidx = (size_t)(rbase + row)*64 + (cg>>1);
            *(uint4*)(Hh2 + oidx) = make_uint4(oh[0],oh[1],oh[2],oh[3]);
            *(uint4*)(Hl2 + oidx) = make_uint4(ol[0],ol[1],ol[2],ol[3]);
        }
        __syncthreads();
    }
}

// ---------------- FUSED GCN layer (frozen at verified 82.9 µs version) ----------------

struct MetaA {
    int   j0A, cA, j0B, cB;
    float dnA, dnB;
    uint32 shA, slA, shB, slB;
};

__device__ __forceinline__ void load_metaA(MetaA& m, int nA, int lane,
                                           const int* __restrict__ rowptr,
                                           const float* __restrict__ dinv,
                                           const uint32* __restrict__ Hh2,
                                           const uint32* __restrict__ Hl2){
    int nB = nA + 8;
    int a0 = rowptr[nA], a1 = rowptr[nA+1];
    int b0 = rowptr[nB], b1 = rowptr[nB+1];
    m.j0A = a0; m.cA = a1 - a0;
    m.j0B = b0; m.cB = b1 - b0;
    m.dnA = dinv[nA]; m.dnB = dinv[nB];
    size_t iA = (size_t)nA*64 + lane, iB = (size_t)nB*64 + lane;
    m.shA = Hh2[iA]; m.slA = Hl2[iA];
    m.shB = Hh2[iB]; m.slB = Hl2[iB];
}

__device__ __forceinline__ void load_jj(int* jjA, int* jjB, const MetaA& m,
                                        const int* __restrict__ csr){
    int jmA = m.j0A + m.cA - 1;
    int jmB = m.j0B + m.cB - 1;
    #pragma unroll
    for(int t=0;t<8;t++){
        int ia = m.j0A + t; ia = ia > jmA ? jmA : ia;
        int ib = m.j0B + t; ib = ib > jmB ? jmB : ib;
        jjA[t] = csr[ia] & (N_NODES-1);
        jjB[t] = csr[ib] & (N_NODES-1);
    }
}

__device__ __forceinline__ void agg_step(
        const MetaA& cur, const int* jjA, const int* jjB, int ii,
        MetaA* m2, int n2,
        int* jj1A, int* jj1B, const MetaA* m1,
        int base16, int lane,
        const uint32* __restrict__ Hh2, const uint32* __restrict__ Hl2,
        const float* __restrict__ dinv, const int* __restrict__ rowptr,
        const int* __restrict__ csr,
        uint32* __restrict__ AhL, uint32* __restrict__ AlL){
    uint32 rrA[8], rrB[8];
    float  wwA[8], wwB[8];
    #pragma unroll
    for(int t=0;t<8;t++){
        wwA[t] = (t < cur.cA) ? dinv[jjA[t]] : 0.f;
        rrA[t] = Hh2[(size_t)jjA[t]*64 + lane];
        wwB[t] = (t < cur.cB) ? dinv[jjB[t]] : 0.f;
        rrB[t] = Hh2[(size_t)jjB[t]*64 + lane];
    }
    if(m2) load_metaA(*m2, n2, lane, rowptr, dinv, Hh2, Hl2);
    if(m1) load_jj(jj1A, jj1B, *m1, csr);
    float axA = (unpack_even(cur.shA) + unpack_even(cur.slA)) * cur.dnA;
    float ayA = (unpack_odd(cur.shA)  + unpack_odd(cur.slA))  * cur.dnA;
    float axB = (unpack_even(cur.shB) + unpack_even(cur.slB)) * cur.dnB;
    float ayB = (unpack_odd(cur.shB)  + unpack_odd(cur.slB))  * cur.dnB;
    #pragma unroll
    for(int t=0;t<8;t++){
        axA = fmaf(unpack_even(rrA[t]), wwA[t], axA);
        ayA = fmaf(unpack_odd(rrA[t]),  wwA[t], ayA);
        axB = fmaf(unpack_even(rrB[t]), wwB[t], axB);
        ayB = fmaf(unpack_odd(rrB[t]),  wwB[t], ayB);
    }
    int nb = cur.cA > cur.cB ? cur.cA : cur.cB;
    if(nb > 8){
        int jmA = cur.j0A + cur.cA - 1;
        int jmB = cur.j0B + cur.cB - 1;
        for(int j=8; j<nb; j+=8){
            int jja[8], jjb[8]; float wa[8], wb[8]; uint32 ra[8], rb[8];
            #pragma unroll
            for(int t=0;t<8;t++){
                int ia = cur.j0A + j + t; ia = ia > jmA ? jmA : ia;
                int ib = cur.j0B + j + t; ib = ib > jmB ? jmB : ib;
                jja[t] = csr[ia] & (N_NODES-1);
                jjb[t] = csr[ib] & (N_NODES-1);
            }
            #pragma unroll
            for(int t=0;t<8;t++){
                wa[t] = (j + t < cur.cA) ? dinv[jja[t]] : 0.f;
                ra[t] = Hh2[(size_t)jja[t]*64 + lane];
                wb[t] = (j + t < cur.cB) ? dinv[jjb[t]] : 0.f;
                rb[t] = Hh2[(size_t)jjb[t]*64 + lane];
            }
            #pragma unroll
            for(int t=0;t<8;t++){
                axA = fmaf(unpack_even(ra[t]), wa[t], axA);
                ayA = fmaf(unpack_odd(ra[t]),  wa[t], ayA);
                axB = fmaf(unpack_even(rb[t]), wb[t], axB);
                ayB = fmaf(unpack_odd(rb[t]),  wb[t], ayB);
            }
        }
    }
    axA *= cur.dnA; ayA *= cur.dnA;
    axB *= cur.dnB; ayB *= cur.dnB;
    int rowA = base16 + ii, rowB = rowA + 8;
    uint32 hxA = bfbits(axA), hyA = bfbits(ayA);
    AhL[rowA*68 + lane] = hxA | (hyA<<16);
    AlL[rowA*68 + lane] = pack2(axA - __uint_as_float(hxA<<16),
                                ayA - __uint_as_float(hyA<<16));
    uint32 hxB = bfbits(axB), hyB = bfbits(ayB);
    AhL[rowB*68 + lane] = hxB | (hyB<<16);
    AlL[rowB*68 + lane] = pack2(axB - __uint_as_float(hxB<<16),
                                ayB - __uint_as_float(hyB<<16));
}

__global__ __launch_bounds__(512, 4)
void k_layer(const __bf16* __restrict__ curHh, const __bf16* __restrict__ curHl,
             const float* __restrict__ dinv, const int* __restrict__ rowptr,
             const int* __restrict__ csr,
             const __bf16* __restrict__ Bth, const __bf16* __restrict__ Btl,
             const float* __restrict__ bias, const float* __restrict__ gamma,
             const float* __restrict__ beta,
             uint32* __restrict__ outHh2, uint32* __restrict__ outHl2, int residual){
    __shared__ uint32 smem[8*32*68];              // 69632 B; A-region then reused as staging
    uint32* AhL = smem;
    uint32* AlL = smem + 128*68;
    int tid  = threadIdx.x;
    int wave = __builtin_amdgcn_readfirstlane(tid >> 6);
    int lane = tid & 63;
    int rbase = blockIdx.x * 128;
    int base16 = wave*16;
    const uint32* Hh2 = (const uint32*)curHh;
    const uint32* Hl2 = (const uint32*)curHl;

    // ---- stage 1: pipelined aggregation, 16 nodes/wave as 8 pairs ----
    {
        MetaA m0, m1, m2;
        int jj0A[8], jj0B[8], jj1A[8], jj1B[8];
        int nb0 = rbase + base16;
        load_metaA(m0, nb0+0, lane, rowptr, dinv, Hh2, Hl2);
        load_metaA(m1, nb0+1, lane, rowptr, dinv, Hh2, Hl2);
        load_jj(jj0A, jj0B, m0, csr);
        agg_step(m0, jj0A, jj0B, 0, &m2, nb0+2, jj1A, jj1B, &m1,
                 base16, lane, Hh2, Hl2, dinv, rowptr, csr, AhL, AlL);
        agg_step(m1, jj1A, jj1B, 1, &m0, nb0+3, jj0A, jj0B, &m2,
                 base16, lane, Hh2, Hl2, dinv, rowptr, csr, AhL, AlL);
        agg_step(m2, jj0A, jj0B, 2, &m1, nb0+4, jj1A, jj1B, &m0,
                 base16, lane, Hh2, Hl2, dinv, rowptr, csr, AhL, AlL);
        agg_step(m0, jj1A, jj1B, 3, &m2, nb0+5, jj0A, jj0B, &m1,
                 base16, lane, Hh2, Hl2, dinv, rowptr, csr, AhL, AlL);
        agg_step(m1, jj0A, jj0B, 4, &m0, nb0+6, jj1A, jj1B, &m2,
                 base16, lane, Hh2, Hl2, dinv, rowptr, csr, AhL, AlL);
        agg_step(m2, jj1A, jj1B, 5, &m1, nb0+7, jj0A, jj0B, &m0,
                 base16, lane, Hh2, Hl2, dinv, rowptr, csr, AhL, AlL);
        agg_step(m0, jj0A, jj0B, 6, nullptr, 0, jj1A, jj1B, &m1,
                 base16, lane, Hh2, Hl2, dinv, rowptr, csr, AhL, AlL);
        agg_step(m1, jj1A, jj1B, 7, nullptr, 0, nullptr, nullptr, nullptr,
                 base16, lane, Hh2, Hl2, dinv, rowptr, csr, AhL, AlL);
    }
    __syncthreads();

    int lr = lane & 15, lq = lane >> 4;
    int wr = wave & 3, wc = wave >> 2;
    int r0 = wr*32;
    bf16x8 A0h[4], A0l[4], A1h[4], A1l[4];
    #pragma unroll
    for(int ks=0;ks<4;ks++){
        int u0 = (r0 + lr)*68 + lq*4 + ks*16;
        int u1 = (r0 + 16 + lr)*68 + lq*4 + ks*16;
        A0h[ks] = __builtin_bit_cast(bf16x8, *(const u32x4*)(AhL + u0));
        A0l[ks] = __builtin_bit_cast(bf16x8, *(const u32x4*)(AlL + u0));
        A1h[ks] = __builtin_bit_cast(bf16x8, *(const u32x4*)(AhL + u1));
        A1l[ks] = __builtin_bit_cast(bf16x8, *(const u32x4*)(AlL + u1));
    }
    __syncthreads();

    float* stg = (float*)smem + wave*(32*68);
    const f32x4 zero4 = {0.f,0.f,0.f,0.f};
    #pragma unroll
    for(int cc=0; cc<4; cc++){
        int col = wc*64 + cc*16 + lr;
        f32x4 a0 = zero4, a1 = zero4;
        #pragma unroll
        for(int ks=0;ks<4;ks++){
            bf16x8 Bh = *(const bf16x8*)(Bth + col*H_DIM + ks*32 + lq*8);
            bf16x8 Bl = *(const bf16x8*)(Btl + col*H_DIM + ks*32 + lq*8);
            a0 = __builtin_amdgcn_mfma_f32_16x16x32_bf16(A0h[ks], Bh, a0, 0,0,0);
            a0 = __builtin_amdgcn_mfma_f32_16x16x32_bf16(A0l[ks], Bh, a0, 0,0,0);
            a0 = __builtin_amdgcn_mfma_f32_16x16x32_bf16(A0h[ks], Bl, a0, 0,0,0);
            a1 = __builtin_amdgcn_mfma_f32_16x16x32_bf16(A1h[ks], Bh, a1, 0,0,0);
            a1 = __builtin_amdgcn_mfma_f32_16x16x32_bf16(A1l[ks], Bh, a1, 0,0,0);
            a1 = __builtin_amdgcn_mfma_f32_16x16x32_bf16(A1h[ks], Bl, a1, 0,0,0);
        }
        #pragma unroll
        for(int r=0;r<4;r++){
            stg[(lq*4+r)*68 + cc*16 + lr]    = a0[r];
            stg[(16+lq*4+r)*68 + cc*16 + lr] = a1[r];
        }
    }

    int orow = lane >> 3;
    int oq   = lane & 7;
    int cg = wc*64 + oq*8;
    float bb[8], gg[8], tt[8];
    *(float4*)&bb[0] = *(const float4*)(bias + cg);
    *(float4*)&bb[4] = *(const float4*)(bias + cg + 4);
    *(float4*)&gg[0] = *(const float4*)(gamma + cg);
    *(float4*)&gg[4] = *(const float4*)(gamma + cg + 4);
    *(float4*)&tt[0] = *(const float4*)(beta + cg);
    *(float4*)&tt[4] = *(const float4*)(beta + cg + 4);
    #pragma unroll
    for(int p=0;p<8;p++) gg[p] *= BN_SCALE;
    #pragma unroll
    for(int i=0;i<4;i++){
        int row = i*8 + orow;
        float v[8];
        *(float4*)&v[0] = *(float4*)&stg[row*68 + oq*8];
        *(float4*)&v[4] = *(float4*)&stg[row*68 + oq*8 + 4];
        size_t oidx = (size_t)(rbase + r0 + row)*64 + (cg>>1);
        uint4 oldh = {0,0,0,0}, oldl = {0,0,0,0};
        if(residual){
            oldh = *(const uint4*)(Hh2 + oidx);
            oldl = *(const uint4*)(Hl2 + oidx);
        }
        uint32 ohv[4] = {oldh.x,oldh.y,oldh.z,oldh.w};
        uint32 olv[4] = {oldl.x,oldl.y,oldl.z,oldl.w};
        uint32 oh[4], ol[4];
        #pragma unroll
        for(int p=0;p<4;p++){
            float ve = fmaxf(fmaf(v[2*p]   + bb[2*p],   gg[2*p],   tt[2*p]),   0.f);
            float vo = fmaxf(fmaf(v[2*p+1] + bb[2*p+1], gg[2*p+1], tt[2*p+1]), 0.f);
            if(residual){
                ve += unpack_even(ohv[p]) + unpack_even(olv[p]);
                vo += unpack_odd(ohv[p])  + unpack_odd(olv[p]);
            }
            uint32 he = bfbits(ve), ho = bfbits(vo);
            oh[p] = he | (ho<<16);
            float le = ve - __uint_as_float(he<<16);
            float lo = vo - __uint_as_float(ho<<16);
            ol[p] = pack2(le, lo);
        }
        *(uint4*)(outHh2 + oidx) = make_uint4(oh[0],oh[1],oh[2],oh[3]);
        *(uint4*)(outHl2 + oidx) = make_uint4(ol[0],ol[1],ol[2],ol[3]);
    }
}

// ---------------- gene GEMM v2: LDS-staged A (dense reads) + frag-linear B ----------------

__global__ __launch_bounds__(256)
void k_gemm_gf_mfma(const float* __restrict__ Agf,
                    const __bf16* __restrict__ Bth, const __bf16* __restrict__ Btl,
                    float* __restrict__ gpart){
    __shared__ float sA[64*34];     // 64 rows x 32 k, stride 34 (conflict-free frag reads)
    int rt = blockIdx.x & 31;       // 32 row tiles of 64
    int sp = blockIdx.x >> 5;       // NSPLIT k-splits
    int ks0 = (sp*138) >> 4, ks1 = ((sp+1)*138) >> 4;
    int tid = threadIdx.x;
    int wave = tid >> 6, lane = tid & 63;
    int lr = lane & 15, lq = lane >> 4;
    int rblk = rt*64;
    int rhalf = (wave & 1)*32;
    int cbase = (wave >> 1)*128;
    const f32x4 zero4 = {0.f,0.f,0.f,0.f};
    f32x4 acc[8][2];
    #pragma unroll
    for(int ct=0;ct<8;ct++){ acc[ct][0] = zero4; acc[ct][1] = zero4; }
    int srow = tid >> 2, sq = tid & 3;                 // staging: thread -> (row, 8-float chunk)
    for(int ks=ks0; ks<ks1; ks++){
        int kc = ks*32;
        __syncthreads();
        // stage A tile (64 rows x 32 k): dense 128-B-per-row reads
        {
            int k0 = kc + sq*8;
            const float* srcp = Agf + (size_t)(rblk + srow)*GF_DIM + k0;
            float v[8];
            if(k0 + 8 <= GF_DIM){
                *(float4*)&v[0] = *(const float4*)srcp;
                *(float4*)&v[4] = *(const float4*)(srcp + 4);
            } else {
                #pragma unroll
                for(int t=0;t<8;t++) v[t] = (k0 + t < GF_DIM) ? srcp[t] : 0.f;
            }
            #pragma unroll
            for(int t=0;t<8;t++) sA[srow*34 + sq*8 + t] = v[t];
        }
        __syncthreads();
        // fragments from LDS + in-register hi/lo split
        bf16x8 A0h, A0l, A1h, A1l;
        {
            const float* a0p = &sA[(rhalf + lr)*34 + lq*8];
            const float* a1p = &sA[(rhalf + 16 + lr)*34 + lq*8];
            #pragma unroll
            for(int t=0;t<8;t++){
                __bf16 h, l;
                split2(a0p[t], h, l); A0h[t] = h; A0l[t] = l;
                split2(a1p[t], h, l); A1h[t] = h; A1l[t] = l;
            }
        }
        // B: frag-linear, each load = contiguous 1 KB per wave
        #pragma unroll
        for(int ct=0;ct<8;ct++){
            size_t bo = ((size_t)((cbase >> 4) + ct)*138 + ks)*512 + lr*32 + lq*8;
            bf16x8 Bh = *(const bf16x8*)(Bth + bo);
            bf16x8 Bl = *(const bf16x8*)(Btl + bo);
            acc[ct][0] = __builtin_amdgcn_mfma_f32_16x16x32_bf16(A0h, Bh, acc[ct][0], 0,0,0);
            acc[ct][0] = __builtin_amdgcn_mfma_f32_16x16x32_bf16(A0l, Bh, acc[ct][0], 0,0,0);
            acc[ct][0] = __builtin_amdgcn_mfma_f32_16x16x32_bf16(A0h, Bl, acc[ct][0], 0,0,0);
            acc[ct][1] = __builtin_amdgcn_mfma_f32_16x16x32_bf16(A1h, Bh, acc[ct][1], 0,0,0);
            acc[ct][1] = __builtin_amdgcn_mfma_f32_16x16x32_bf16(A1l, Bh, acc[ct][1], 0,0,0);
            acc[ct][1] = __builtin_amdgcn_mfma_f32_16x16x32_bf16(A1h, Bl, acc[ct][1], 0,0,0);
        }
    }
    float* po = gpart + (size_t)sp*(B_GR*256);
    #pragma unroll
    for(int ct=0;ct<8;ct++)
        #pragma unroll
        for(int s=0;s<2;s++)
            #pragma unroll
            for(int r=0;r<4;r++)
                po[(size_t)(rblk + rhalf + s*16 + lq*4 + r)*256 + cbase + ct*16 + lr] = acc[ct][s][r];
}

// sum NSPLIT partials -> raw g1acc (epilogue applied in k_head)
__global__ void k_gene_reduce(const float* __restrict__ gpart, float* __restrict__ g1acc){
    int i = blockIdx.x*256 + threadIdx.x;   // B*256
    float v = 0.f;
    #pragma unroll 8
    for(int sp=0;sp<NSPLIT;sp++) v += gpart[(size_t)sp*(B_GR*256) + i];
    g1acc[i] = v;
}

// ---------------- FUSED head v4: 8 graphs/block, LDS weights; g1 epilogue folded in ----

__device__ __forceinline__ void load_w4(const float* __restrict__ W, int off, int tid,
                                        float4* t){
    const float4* s = (const float4*)(W + off);
    t[0] = s[tid];
    t[1] = s[tid + 512];
    t[2] = s[tid + 1024];
    t[3] = s[tid + 1536];
}
__device__ __forceinline__ void write_w4(float* sW, int tid, const float4* t){
    float4* d = (float4*)sW;
    d[tid]        = t[0];
    d[tid + 512]  = t[1];
    d[tid + 1024] = t[2];
    d[tid + 1536] = t[3];
}

__device__ __forceinline__ void dense_stage128(
        const float* __restrict__ W, int nck, const float* sA, int lda,
        float* sO, int ldo, float* sW, int tid, int c, int ga, int gb,
        float bias_c, float gsc, float bsh, int do_relu){
    float4 t[4];
    load_w4(W, 0, tid, t);
    write_w4(sW, tid, t);
    __syncthreads();
    float a0 = bias_c, a1 = bias_c;
    for(int ck=0; ck<nck; ck++){
        if(ck+1 < nck) load_w4(W, (ck+1)*8192, tid, t);
        const float* aga = sA + ga*lda + ck*64;
        const float* agb = sA + gb*lda + ck*64;
        #pragma unroll
        for(int k=0;k<64;k++){
            float w = sW[k*128 + c];
            a0 = fmaf(aga[k], w, a0);
            a1 = fmaf(agb[k], w, a1);
        }
        __syncthreads();
        if(ck+1 < nck){ write_w4(sW, tid, t); __syncthreads(); }
    }
    a0 = fmaf(a0, gsc, bsh);
    a1 = fmaf(a1, gsc, bsh);
    if(do_relu){ a0 = fmaxf(a0, 0.f); a1 = fmaxf(a1, 0.f); }
    sO[ga*ldo + c] = a0;
    sO[gb*ldo + c] = a1;
}

__global__ __launch_bounds__(512)
void k_head(const uint32* __restrict__ Hh2, const uint32* __restrict__ Hl2,
            const float* __restrict__ g1acc,
            const float* __restrict__ bge1, const float* __restrict__ g_g,
            const float* __restrict__ g_b,
            const float* __restrict__ Wd1, const float* __restrict__ bd1,
            const float* __restrict__ Wd2, const float* __restrict__ bd2,
            const float* __restrict__ Wge2, const float* __restrict__ bge2,
            const float* __restrict__ Wh1, const float* __restrict__ bh1,
            const float* __restrict__ h_g, const float* __restrict__ h_b,
            const float* __restrict__ Wh2, const float* __restrict__ bh2,
            const float* __restrict__ Wh3, const float* __restrict__ bh3,
            float* __restrict__ out){
    __shared__ float sPool[8][256];
    __shared__ float sG1[8][256];
    __shared__ float sT1[8][128];
    __shared__ float sComb[8][256];
    __shared__ float sZ[8][128];
    __shared__ float sZ2[8][64];
    __shared__ float sW[8192];          // 32 KB weight chunk
    int tid = threadIdx.x;
    int wave = tid >> 6, lane = tid & 63;
    int g0 = blockIdx.x*8;
    // g1 = relu((g1acc + bge1) * g_g*BN_SCALE + g_b), folded into the LDS load
    {
        int idx = tid*4;                 // 0..2047
        int g = idx >> 8, c = idx & 255;
        float4 a  = *(const float4*)&g1acc[(size_t)(g0+g)*256 + c];
        float4 b  = *(const float4*)&bge1[c];
        float4 gm = *(const float4*)&g_g[c];
        float4 bt = *(const float4*)&g_b[c];
        sG1[g][c+0] = fmaxf(fmaf(a.x + b.x, gm.x*BN_SCALE, bt.x), 0.f);
        sG1[g][c+1] = fmaxf(fmaf(a.y + b.y, gm.y*BN_SCALE, bt.y), 0.f);
        sG1[g][c+2] = fmaxf(fmaf(a.z + b.z, gm.z*BN_SCALE, bt.z), 0.f);
        sG1[g][c+3] = fmaxf(fmaf(a.w + b.w, gm.w*BN_SCALE, bt.w), 0.f);
    }
    {
        size_t base = (size_t)(g0+wave)*4096 + lane;
        float se = 0.f, so = 0.f, me = -3.4e38f, mo = -3.4e38f;
        #pragma unroll 8
        for(int r=0;r<64;r++){
            uint32 h = Hh2[base + r*64];
            uint32 l = Hl2[base + r*64];
            float ve = unpack_even(h) + unpack_even(l);
            float vo = unpack_odd(h)  + unpack_odd(l);
            se += ve; so += vo;
            me = fmaxf(me, ve); mo = fmaxf(mo, vo);
        }
        sPool[wave][2*lane]       = se*(1.f/64.f);
        sPool[wave][2*lane+1]     = so*(1.f/64.f);
        sPool[wave][128+2*lane]   = me;
        sPool[wave][128+2*lane+1] = mo;
    }
    __syncthreads();
    int c = tid & 127, q = tid >> 7;     // q in 0..3 -> graphs 2q, 2q+1
    int ga = 2*q, gb = 2*q + 1;
    dense_stage128(Wd1, 4, &sPool[0][0], 256, &sT1[0][0], 128, sW, tid, c, ga, gb,
                   bd1[c], 1.f, 0.f, 1);
    dense_stage128(Wd2, 2, &sT1[0][0], 128, &sComb[0][0], 256, sW, tid, c, ga, gb,
                   bd2[c], 1.f, 0.f, 0);
    dense_stage128(Wge2, 4, &sG1[0][0], 256, &sComb[0][0] + 128, 256, sW, tid, c, ga, gb,
                   bge2[c], 1.f, 0.f, 1);
    dense_stage128(Wh1, 4, &sComb[0][0], 256, &sZ[0][0], 128, sW, tid, c, ga, gb,
                   bh1[c], h_g[c]*BN_SCALE, h_b[c], 1);
    {
        float4 t[4];
        load_w4(Wh2, 0, tid, t);
        write_w4(sW, tid, t);
        __syncthreads();
        int c2 = tid & 63, q2 = tid >> 6;     // q2 = graph
        float a = bh2[c2];
        #pragma unroll
        for(int k=0;k<128;k++)
            a = fmaf(sZ[q2][k], sW[k*64 + c2], a);
        sZ2[q2][c2] = fmaxf(a, 0.f);
    }
    __syncthreads();
    {
        float v = sZ2[wave][lane] * Wh3[lane];
        #pragma unroll
        for(int off=32; off; off>>=1) v += __shfl_down(v, off);
        if(lane == 0) out[g0 + wave] = v + bh3[0];
    }
}

// ---------------- launch ----------------

extern "C" void kernel_launch(void* const* d_in, const int* in_sizes, int n_in,
                              void* d_out, int out_size, void* d_ws, size_t ws_size,
                              hipStream_t stream){
    (void)in_sizes; (void)n_in; (void)out_size; (void)ws_size;
    const float* x    = (const float*)d_in[0];
    const float* gf   = (const float*)d_in[1];
    const int*   ei   = (const int*)  d_in[2];
    const float* W_emb= (const float*)d_in[4];
    const float* b_emb= (const float*)d_in[5];
    const float* Wg   = (const float*)d_in[6];
    const float* bg   = (const float*)d_in[7];
    const float* bn_g = (const float*)d_in[8];
    const float* bn_b = (const float*)d_in[9];
    const float* Wd1  = (const float*)d_in[10];
    const float* bd1  = (const float*)d_in[11];
    const float* Wd2  = (const float*)d_in[12];
    const float* bd2  = (const float*)d_in[13];
    const float* Wge1 = (const float*)d_in[14];
    const float* bge1 = (const float*)d_in[15];
    const float* g_g  = (const float*)d_in[16];
    const float* g_b  = (const float*)d_in[17];
    const float* Wge2 = (const float*)d_in[18];
    const float* bge2 = (const float*)d_in[19];
    const float* Wh1  = (const float*)d_in[20];
    const float* bh1  = (const float*)d_in[21];
    const float* h_g  = (const float*)d_in[22];
    const float* h_b  = (const float*)d_in[23];
    const float* Wh2  = (const float*)d_in[24];
    const float* bh2  = (const float*)d_in[25];
    const float* Wh3  = (const float*)d_in[26];
    const float* bh3  = (const float*)d_in[27];
    float* outp = (float*)d_out;

    char* base = (char*)d_ws;
    __bf16* Hh = (__bf16*)base;                              // 32 MiB (ping)
    __bf16* Hl = (__bf16*)(base + (32u<<20));                // 32 MiB
    __bf16* Ph = (__bf16*)(base + (64u<<20));                // 32 MiB (pong)
    __bf16* Pl = (__bf16*)(base + (96u<<20));                // 32 MiB
    // gene scratch: gpart (32 MiB) in Hh region (dead until k_emb); wge in Ph region
    float*  gpart  = (float*)base;                           // 16 x 2 MiB = 32 MiB
    __bf16* wge_th = (__bf16*)(base + (64u<<20));            // 2,260,992 B
    __bf16* wge_tl = (__bf16*)(base + (64u<<20) + 2260992);  // ends < 69 MiB
    // tail:
    char* T = base + (128u<<20);
    float* g1acc = (float*)T;                                // 2 MiB (summed partials)
    int* counts = (int*)(g1acc + B_GR*256);
    int* rowptr = counts + N_NODES;
    int* cursor = rowptr + (N_NODES+1);
    int* csr    = cursor + N_NODES;
    int* bsums  = csr + E_EDGES;
    float* dinv = (float*)(bsums + 128);
    __bf16* wg_th = (__bf16*)(dinv + N_NODES);               // 3*16384
    __bf16* wg_tl = wg_th + 3*16384;
    __bf16* we_th = wg_tl + 3*16384;                         // 128*32
    __bf16* we_tl = we_th + 128*32;

    const int* src = ei;
    const int* dst = ei + E_EDGES;

    // weights split (Wge1 frag-linear + Wg + Wemb in one launch)
    k_split_weights<<<484, 256, 0, stream>>>(Wge1, wge_th, wge_tl, Wg, wg_th, wg_tl,
                                             W_emb, we_th, we_tl);

    // gene GEMM v2 + reduce (gpart in Hh region, consumed before k_emb)
    k_gemm_gf_mfma<<<32*NSPLIT, 256, 0, stream>>>(gf, wge_th, wge_tl, gpart);
    k_gene_reduce <<<(B_GR*256)/256, 256, 0, stream>>>(gpart, g1acc);

    // graph prep
    k_zero_int<<<N_NODES/256, 256, 0, stream>>>(counts, N_NODES);
    k_count<<<E_EDGES/256, 256, 0, stream>>>(dst, counts);
    k_scan1<<<128, 1024, 0, stream>>>(counts, bsums);
    k_scan2<<<1, 128, 0, stream>>>(bsums);
    k_scan3<<<128, 1024, 0, stream>>>(counts, bsums, rowptr, dinv, cursor);
    k_fill <<<E_EDGES/256, 256, 0, stream>>>(src, dst, cursor, csr);

    // embedding (fused x split)
    k_emb_mfma<<<N_NODES/128, 256, 0, stream>>>(x, we_th, we_tl, b_emb,
                                                (uint32*)Hh, (uint32*)Hl);

    // 3 fused GCN layers, ping-pong (Hh,Hl) <-> (Ph,Pl)
    uint32 *curh = (uint32*)Hh, *curl = (uint32*)Hl;
    uint32 *outh = (uint32*)Ph, *outl = (uint32*)Pl;
    for(int i=0;i<3;i++){
        k_layer<<<N_NODES/128, 512, 0, stream>>>((const __bf16*)curh, (const __bf16*)curl,
                                                 dinv, rowptr, csr,
                                                 wg_th + i*16384, wg_tl + i*16384,
                                                 bg + i*H_DIM, bn_g + i*H_DIM, bn_b + i*H_DIM,
                                                 outh, outl, i > 0);
        uint32* th = curh; curh = outh; outh = th;
        uint32* tl = curl; curl = outl; outl = tl;
    }

    // fused head v4 (g1 epilogue folded); final H is in (curh, curl)
    k_head<<<B_GR/8, 512, 0, stream>>>(curh, curl, g1acc, bge1, g_g, g_b,
                                       Wd1, bd1, Wd2, bd2, Wge2, bge2,
                                       Wh1, bh1, h_g, h_b, Wh2, bh2, Wh3, bh3, outp);
}